// Round 1
// baseline (889.177 us; speedup 1.0000x reference)
//
#include <hip/hip_runtime.h>
#include <hip/hip_bf16.h>
#include <cstdint>
#include <cstddef>

#define NN 500000
#define NG 10000
#define F  128
#define EPSV 1e-5f

typedef __attribute__((ext_vector_type(8))) short short8;
typedef __attribute__((ext_vector_type(4))) float floatx4;

__device__ __forceinline__ short bfs(float f) {
    __hip_bfloat16 h = __float2bfloat16(f);   // HW cvt, RNE
    union { __hip_bfloat16 h; unsigned short u; } c; c.h = h;
    return (short)c.u;
}
// batch may arrive as int32 (harness-converted) or raw int64 (little-endian, values < 10000).
__device__ __forceinline__ int getb(const int* __restrict__ b, int i, int is64) {
    return is64 ? b[2 * i] : b[i];
}

// ---- K0: detect batch dtype. Sorted int32 batch has nonzero values at odd positions >= 100001;
// int64 batch has all-zero high words there. flag = 1 -> int64.
__global__ void k_detect(const int* __restrict__ batch, int* __restrict__ flag) {
    __shared__ int nz;
    if (threadIdx.x == 0) nz = 0;
    __syncthreads();
    int j = 100001 + threadIdx.x * 1500;      // odd indices, max 482501 < 500000
    if (batch[j] != 0) atomicAdd(&nz, 1);
    __syncthreads();
    if (threadIdx.x == 0) flag[0] = (nz == 0) ? 1 : 0;
}

// ---- K1: segment boundaries (batch is sorted). Empty graphs keep start=end=0 via memset.
__global__ void k_bounds(const int* __restrict__ batch, int* __restrict__ gs, int* __restrict__ ge,
                         const int* __restrict__ flag) {
    int is64 = flag[0];
    int i = blockIdx.x * 256 + threadIdx.x;
    if (i >= NN) return;
    int b = getb(batch, i, is64);
    if (i == 0      || getb(batch, i - 1, is64) != b) gs[b] = i;
    if (i == NN - 1 || getb(batch, i + 1, is64) != b) ge[b] = i + 1;
}

// ---- K2: per-graph segment sum (fp32), one block per graph. 256 thr = 32 float4-cols x 8 rows.
//          Also emits xb = bf16(x) (fragment-consumable row-major) when xb != nullptr.
__global__ void k_segsum(const float* __restrict__ x, const int* __restrict__ gs,
                         const int* __restrict__ ge, float* __restrict__ S,
                         unsigned short* __restrict__ xb) {
    __shared__ float red[8][128];
    int g = blockIdx.x;
    int s = gs[g], e = ge[g];
    int o = threadIdx.x & 31, rl = threadIdx.x >> 5;
    float acc[4] = {0.f, 0.f, 0.f, 0.f};
    for (int r = s + rl; r < e; r += 8) {
        float4 v = *reinterpret_cast<const float4*>(x + (size_t)r * F + o * 4);
        acc[0] += v.x; acc[1] += v.y; acc[2] += v.z; acc[3] += v.w;
        if (xb) {
            ushort4 bv;
            bv.x = (unsigned short)bfs(v.x); bv.y = (unsigned short)bfs(v.y);
            bv.z = (unsigned short)bfs(v.z); bv.w = (unsigned short)bfs(v.w);
            *reinterpret_cast<ushort4*>(xb + (size_t)r * F + o * 4) = bv;
        }
    }
#pragma unroll
    for (int j = 0; j < 4; j++) red[rl][o * 4 + j] = acc[j];
    __syncthreads();
    if (threadIdx.x < 128) {
        float ssum = 0.f;
#pragma unroll
        for (int rr = 0; rr < 8; rr++) ssum += red[rr][threadIdx.x];
        S[(size_t)g * F + threadIdx.x] = ssum;
    }
}

// ---- K2b: fragment-ordered bf16 weight tables: Wf[n*128 + k] = bf16(W[k*128 + n]).
//           A lane's B-fragment chunk (8 consecutive k at fixed n) is then one 16B load.
__global__ void k_wfrag(const float* __restrict__ W1, const float* __restrict__ W2,
                        unsigned short* __restrict__ W1f, unsigned short* __restrict__ W2f) {
    int i = blockIdx.x * 256 + threadIdx.x;   // grid 128*256 = 32768 = 2*16384
    int sel = i >> 14, j = i & 16383;
    int n = j >> 7, kk = j & 127;
    const float* W = sel ? W2 : W1;
    unsigned short* Wf = sel ? W2f : W1f;
    Wf[j] = (unsigned short)bfs(W[kk * F + n]);
}

// ---- K3a/K3e: out[r][c] = (bias?) + sum_k A[r][k] * W[k][c].  10000x128, K=128, all fp32. 2 rows/block.
__global__ void k_rowmm(const float* __restrict__ A, const float* __restrict__ W,
                        const float* __restrict__ bias, float* __restrict__ out, int hasBias) {
    int r = blockIdx.x * 2 + (threadIdx.x >> 7);
    int c = threadIdx.x & 127;
    const float* a = A + (size_t)r * F;
    float acc = hasBias ? bias[c] : 0.f;
#pragma unroll 4
    for (int k = 0; k < F; k++) acc += a[k] * W[k * F + c];
    out[(size_t)r * F + c] = acc;
}

// ---- K3b: column sums / sumsq of T over 10000 rows (for BN0). grid 64 x 128.
__global__ void k_colstats(const float* __restrict__ T, float* __restrict__ sum, float* __restrict__ sumsq) {
    int f = threadIdx.x;
    int lo = blockIdx.x * 157;              // 64*157 = 10048 >= 10000
    int hi = lo + 157; if (hi > NG) hi = NG;
    float s = 0.f, q = 0.f;
    for (int r = lo; r < hi; r++) { float v = T[(size_t)r * F + f]; s += v; q += v * v; }
    atomicAdd(&sum[f], s); atomicAdd(&sumsq[f], q);
}

// ---- K3c: finalize BN0 -> per-feature scale/shift.
__global__ void k_bn0(const float* __restrict__ sum, const float* __restrict__ sumsq,
                      const float* __restrict__ g, const float* __restrict__ b,
                      float* __restrict__ scale, float* __restrict__ shift) {
    int f = threadIdx.x;
    float mu  = sum[f] / (float)NG;
    float var = sumsq[f] / (float)NG - mu * mu;
    float rs  = rsqrtf(var + EPSV);
    float sc  = g[f] * rs;
    scale[f] = sc; shift[f] = b[f] - mu * sc;
}

// ---- K3d: S2f = relu(T*scale + shift), f32. grid 1250 x 256, 4 elems/thread.
__global__ void k_bnrelu(const float* __restrict__ T, const float* __restrict__ scale,
                         const float* __restrict__ shift, float* __restrict__ S2) {
    int e = (blockIdx.x * 256 + threadIdx.x) * 4;
    float4 t = *reinterpret_cast<const float4*>(T + e);
    int c = e & 127;
    float4 o;
    o.x = fmaxf(t.x * scale[c]     + shift[c],     0.f);
    o.y = fmaxf(t.y * scale[c + 1] + shift[c + 1], 0.f);
    o.z = fmaxf(t.z * scale[c + 2] + shift[c + 2], 0.f);
    o.w = fmaxf(t.w * scale[c + 3] + shift[c + 3], 0.f);
    *reinterpret_cast<float4*>(S2 + e) = o;
}

// load 8 consecutive fp32 and convert to a bf16 A/B fragment chunk (legacy path)
__device__ __forceinline__ short8 ld8bf(const float* __restrict__ p) {
    float4 f0 = *reinterpret_cast<const float4*>(p);
    float4 f1 = *reinterpret_cast<const float4*>(p + 4);
    short8 r;
    r[0] = bfs(f0.x); r[1] = bfs(f0.y); r[2] = bfs(f0.z); r[3] = bfs(f0.w);
    r[4] = bfs(f1.x); r[5] = bfs(f1.y); r[6] = bfs(f1.z); r[7] = bfs(f1.w);
    return r;
}

// ======================= NEW PATH: bf16 x + fragment weight tables =======================

// ---- K4: pass1. u = xb@W1 + Z[batch] (Z folds b1); accumulate per-feature sum/sumsq of u.
__global__ __launch_bounds__(256, 4)
void k_pass1(const unsigned short* __restrict__ xb, const int* __restrict__ batch,
             const unsigned short* __restrict__ W1f, const float* __restrict__ Z,
             float* __restrict__ partials, const int* __restrict__ flag) {
    const int is64 = flag[0];
    const int lane = threadIdx.x & 63;
    const int wave = threadIdx.x >> 6;
    const int wm = wave & 1, wn = wave >> 1;
    const int quad = lane >> 4, l16 = lane & 15;

    const unsigned short* wbase = W1f + ((wn * 64 + l16) * F + quad * 8);

    float su[4], sq[4];
#pragma unroll
    for (int nt = 0; nt < 4; nt++) { su[nt] = 0.f; sq[nt] = 0.f; }

    const int NT = (NN + 63) / 64;
    for (int tile = blockIdx.x; tile < NT; tile += gridDim.x) {
        int rb = tile * 64 + wm * 32;
        floatx4 acc[2][4];
#pragma unroll
        for (int mt = 0; mt < 2; mt++)
#pragma unroll
            for (int nt = 0; nt < 4; nt++) acc[mt][nt] = (floatx4){0.f, 0.f, 0.f, 0.f};

#pragma unroll
        for (int kt = 0; kt < 4; kt++) {
            short8 A[2];
#pragma unroll
            for (int mt = 0; mt < 2; mt++) {
                int r = rb + mt * 16 + l16; if (r >= NN) r = NN - 1;
                A[mt] = *reinterpret_cast<const short8*>(xb + (size_t)r * F + kt * 32 + quad * 8);
            }
#pragma unroll
            for (int nt = 0; nt < 4; nt++) {
                short8 B = *reinterpret_cast<const short8*>(wbase + nt * 16 * F + kt * 32);
#pragma unroll
                for (int mt = 0; mt < 2; mt++)
                    acc[mt][nt] = __builtin_amdgcn_mfma_f32_16x16x32_bf16(A[mt], B, acc[mt][nt], 0, 0, 0);
            }
        }

#pragma unroll
        for (int mt = 0; mt < 2; mt++)
#pragma unroll
            for (int reg = 0; reg < 4; reg++) {
                int r = rb + mt * 16 + quad * 4 + reg;
                bool valid = r < NN;
                int g = getb(batch, valid ? r : NN - 1, is64);
                const float* zr = Z + (size_t)g * F + wn * 64 + l16;
#pragma unroll
                for (int nt = 0; nt < 4; nt++) {
                    float u = acc[mt][nt][reg] + zr[nt * 16];
                    if (valid) { su[nt] += u; sq[nt] += u * u; }
                }
            }
    }

    float* ps = partials + (size_t)(blockIdx.x & 63) * 256;
#pragma unroll
    for (int nt = 0; nt < 4; nt++) {
        float s = su[nt], q = sq[nt];
        s += __shfl_xor(s, 16, 64); s += __shfl_xor(s, 32, 64);
        q += __shfl_xor(q, 16, 64); q += __shfl_xor(q, 32, 64);
        if (quad == 0) {
            int col = wn * 64 + nt * 16 + l16;
            atomicAdd(&ps[col], s);
            atomicAdd(&ps[128 + col], q);
        }
    }
}

// ---- K5: finalize BN1 from 64 partial slots.
__global__ void k_bn1(const float* __restrict__ partials, const float* __restrict__ g1,
                      const float* __restrict__ b1g, float* __restrict__ scale1,
                      float* __restrict__ shift1) {
    int f = threadIdx.x;
    float s = 0.f, q = 0.f;
    for (int t = 0; t < 64; t++) { s += partials[t * 256 + f]; q += partials[t * 256 + 128 + f]; }
    float mu  = s / (float)NN;
    float var = q / (float)NN - mu * mu;
    float rs  = rsqrtf(var + EPSV);
    float sc  = g1[f] * rs;
    scale1[f] = sc; shift1[f] = b1g[f] - mu * sc;
}

// ---- K6: pass2. Recompute u, h2 = relu(u*scale1+shift1) -> LDS bf16 (double-buffered),
//          out = h2@W2 + b2 written fp32. W1f/W2f/out deliberately NOT restrict so B-frag
//          loads cannot be hoisted into 128 resident VGPRs (streamed from L1/L2 instead).
__global__ __launch_bounds__(256, 4)
void k_pass2(const unsigned short* __restrict__ xb, const int* __restrict__ batch,
             const unsigned short* W1f, const unsigned short* W2f,
             const float* __restrict__ Z, const float* __restrict__ scale1,
             const float* __restrict__ shift1, const float* __restrict__ b2,
             float* out, const int* __restrict__ flag) {
    __shared__ unsigned short h2[2][64][136];   // pad 8 -> conflict-light; double buffer -> 1 sync/tile
    const int is64 = flag[0];
    const int lane = threadIdx.x & 63;
    const int wave = threadIdx.x >> 6;
    const int wm = wave & 1, wn = wave >> 1;
    const int quad = lane >> 4, l16 = lane & 15;

    float sc1[4], sh1[4], bb2[4];
#pragma unroll
    for (int nt = 0; nt < 4; nt++) {
        int n = wn * 64 + nt * 16 + l16;
        sc1[nt] = scale1[n]; sh1[nt] = shift1[n]; bb2[nt] = b2[n];
    }
    const unsigned short* w1base = W1f + ((wn * 64 + l16) * F + quad * 8);
    const unsigned short* w2base = W2f + ((wn * 64 + l16) * F + quad * 8);

    int buf = 0;
    const int NT = (NN + 63) / 64;
    for (int tile = blockIdx.x; tile < NT; tile += gridDim.x) {
        int rb = tile * 64 + wm * 32;
        floatx4 acc[2][4];
#pragma unroll
        for (int mt = 0; mt < 2; mt++)
#pragma unroll
            for (int nt = 0; nt < 4; nt++) acc[mt][nt] = (floatx4){0.f, 0.f, 0.f, 0.f};

#pragma unroll
        for (int kt = 0; kt < 4; kt++) {
            short8 A[2];
#pragma unroll
            for (int mt = 0; mt < 2; mt++) {
                int r = rb + mt * 16 + l16; if (r >= NN) r = NN - 1;
                A[mt] = *reinterpret_cast<const short8*>(xb + (size_t)r * F + kt * 32 + quad * 8);
            }
#pragma unroll
            for (int nt = 0; nt < 4; nt++) {
                short8 B = *reinterpret_cast<const short8*>(w1base + nt * 16 * F + kt * 32);
#pragma unroll
                for (int mt = 0; mt < 2; mt++)
                    acc[mt][nt] = __builtin_amdgcn_mfma_f32_16x16x32_bf16(A[mt], B, acc[mt][nt], 0, 0, 0);
            }
        }

#pragma unroll
        for (int mt = 0; mt < 2; mt++)
#pragma unroll
            for (int reg = 0; reg < 4; reg++) {
                int lr = wm * 32 + mt * 16 + quad * 4 + reg;
                int r = tile * 64 + lr; if (r >= NN) r = NN - 1;
                int g = getb(batch, r, is64);
                const float* zr = Z + (size_t)g * F + wn * 64 + l16;
#pragma unroll
                for (int nt = 0; nt < 4; nt++) {
                    float u = acc[mt][nt][reg] + zr[nt * 16];
                    float h = fmaxf(u * sc1[nt] + sh1[nt], 0.f);
                    h2[buf][lr][wn * 64 + nt * 16 + l16] = (unsigned short)bfs(h);
                }
            }
        __syncthreads();

        floatx4 acc2[2][4];
#pragma unroll
        for (int mt = 0; mt < 2; mt++)
#pragma unroll
            for (int nt = 0; nt < 4; nt++) acc2[mt][nt] = (floatx4){0.f, 0.f, 0.f, 0.f};
#pragma unroll
        for (int kt = 0; kt < 4; kt++) {
            short8 A2[2];
#pragma unroll
            for (int mt = 0; mt < 2; mt++)
                A2[mt] = *reinterpret_cast<const short8*>(&h2[buf][wm * 32 + mt * 16 + l16][kt * 32 + quad * 8]);
#pragma unroll
            for (int nt = 0; nt < 4; nt++) {
                short8 B = *reinterpret_cast<const short8*>(w2base + nt * 16 * F + kt * 32);
#pragma unroll
                for (int mt = 0; mt < 2; mt++)
                    acc2[mt][nt] = __builtin_amdgcn_mfma_f32_16x16x32_bf16(A2[mt], B, acc2[mt][nt], 0, 0, 0);
            }
        }

#pragma unroll
        for (int mt = 0; mt < 2; mt++)
#pragma unroll
            for (int reg = 0; reg < 4; reg++) {
                int r = rb + mt * 16 + quad * 4 + reg;
                if (r < NN) {
#pragma unroll
                    for (int nt = 0; nt < 4; nt++)
                        out[(size_t)r * F + wn * 64 + nt * 16 + l16] = acc2[mt][nt][reg] + bb2[nt];
                }
            }
        buf ^= 1;
    }
}

// ======================= LEGACY PATH (exact previous kernels; used if workspace too small) =======================

__global__ __launch_bounds__(256, 2)
void k_pass1_old(const float* __restrict__ x, const int* __restrict__ batch,
                 const float* __restrict__ W1, const float* __restrict__ Z,
                 float* __restrict__ partials, const int* __restrict__ flag) {
    const int is64 = flag[0];
    const int lane = threadIdx.x & 63;
    const int wave = threadIdx.x >> 6;
    const int wm = wave & 1, wn = wave >> 1;
    const int quad = lane >> 4, l16 = lane & 15;

    short8 Bf[4][4];
#pragma unroll
    for (int nt = 0; nt < 4; nt++) {
        int n = wn * 64 + nt * 16 + l16;
#pragma unroll
        for (int kt = 0; kt < 4; kt++)
#pragma unroll
            for (int j = 0; j < 8; j++)
                Bf[nt][kt][j] = bfs(W1[(kt * 32 + quad * 8 + j) * F + n]);
    }

    float su[4], sq[4];
#pragma unroll
    for (int nt = 0; nt < 4; nt++) { su[nt] = 0.f; sq[nt] = 0.f; }

    const int NT = (NN + 63) / 64;
    for (int tile = blockIdx.x; tile < NT; tile += gridDim.x) {
        int rb = tile * 64 + wm * 32;
        floatx4 acc[2][4];
#pragma unroll
        for (int mt = 0; mt < 2; mt++)
#pragma unroll
            for (int nt = 0; nt < 4; nt++) acc[mt][nt] = (floatx4){0.f, 0.f, 0.f, 0.f};

#pragma unroll
        for (int kt = 0; kt < 4; kt++) {
            short8 A[2];
#pragma unroll
            for (int mt = 0; mt < 2; mt++) {
                int r = rb + mt * 16 + l16; if (r >= NN) r = NN - 1;
                A[mt] = ld8bf(x + (size_t)r * F + kt * 32 + quad * 8);
            }
#pragma unroll
            for (int mt = 0; mt < 2; mt++)
#pragma unroll
                for (int nt = 0; nt < 4; nt++)
                    acc[mt][nt] = __builtin_amdgcn_mfma_f32_16x16x32_bf16(A[mt], Bf[nt][kt], acc[mt][nt], 0, 0, 0);
        }

#pragma unroll
        for (int mt = 0; mt < 2; mt++)
#pragma unroll
            for (int reg = 0; reg < 4; reg++) {
                int r = rb + mt * 16 + quad * 4 + reg;
                bool valid = r < NN;
                int g = getb(batch, valid ? r : NN - 1, is64);
                const float* zr = Z + (size_t)g * F + wn * 64 + l16;
#pragma unroll
                for (int nt = 0; nt < 4; nt++) {
                    float u = acc[mt][nt][reg] + zr[nt * 16];
                    if (valid) { su[nt] += u; sq[nt] += u * u; }
                }
            }
    }

    float* ps = partials + (size_t)(blockIdx.x & 63) * 256;
#pragma unroll
    for (int nt = 0; nt < 4; nt++) {
        float s = su[nt], q = sq[nt];
        s += __shfl_xor(s, 16, 64); s += __shfl_xor(s, 32, 64);
        q += __shfl_xor(q, 16, 64); q += __shfl_xor(q, 32, 64);
        if (quad == 0) {
            int col = wn * 64 + nt * 16 + l16;
            atomicAdd(&ps[col], s);
            atomicAdd(&ps[128 + col], q);
        }
    }
}

__global__ __launch_bounds__(256, 2)
void k_pass2_old(const float* __restrict__ x, const int* __restrict__ batch,
                 const float* __restrict__ W1, const float* __restrict__ W2,
                 const float* __restrict__ Z, const float* __restrict__ scale1,
                 const float* __restrict__ shift1, const float* __restrict__ b2,
                 float* __restrict__ out, const int* __restrict__ flag) {
    extern __shared__ unsigned short h2[];   // [64][136]
    const int is64 = flag[0];
    const int lane = threadIdx.x & 63;
    const int wave = threadIdx.x >> 6;
    const int wm = wave & 1, wn = wave >> 1;
    const int quad = lane >> 4, l16 = lane & 15;

    short8 Bf1[4][4], Bf2[4][4];
    float sc1[4], sh1[4], bb2[4];
#pragma unroll
    for (int nt = 0; nt < 4; nt++) {
        int n = wn * 64 + nt * 16 + l16;
        sc1[nt] = scale1[n]; sh1[nt] = shift1[n]; bb2[nt] = b2[n];
#pragma unroll
        for (int kt = 0; kt < 4; kt++)
#pragma unroll
            for (int j = 0; j < 8; j++) {
                int k = kt * 32 + quad * 8 + j;
                Bf1[nt][kt][j] = bfs(W1[k * F + n]);
                Bf2[nt][kt][j] = bfs(W2[k * F + n]);
            }
    }

    const int NT = (NN + 63) / 64;
    for (int tile = blockIdx.x; tile < NT; tile += gridDim.x) {
        int rb = tile * 64 + wm * 32;
        floatx4 acc[2][4];
#pragma unroll
        for (int mt = 0; mt < 2; mt++)
#pragma unroll
            for (int nt = 0; nt < 4; nt++) acc[mt][nt] = (floatx4){0.f, 0.f, 0.f, 0.f};

#pragma unroll
        for (int kt = 0; kt < 4; kt++) {
            short8 A[2];
#pragma unroll
            for (int mt = 0; mt < 2; mt++) {
                int r = rb + mt * 16 + l16; if (r >= NN) r = NN - 1;
                A[mt] = ld8bf(x + (size_t)r * F + kt * 32 + quad * 8);
            }
#pragma unroll
            for (int mt = 0; mt < 2; mt++)
#pragma unroll
                for (int nt = 0; nt < 4; nt++)
                    acc[mt][nt] = __builtin_amdgcn_mfma_f32_16x16x32_bf16(A[mt], Bf1[nt][kt], acc[mt][nt], 0, 0, 0);
        }

        __syncthreads();
#pragma unroll
        for (int mt = 0; mt < 2; mt++)
#pragma unroll
            for (int reg = 0; reg < 4; reg++) {
                int lr = wm * 32 + mt * 16 + quad * 4 + reg;
                int r = tile * 64 + lr; if (r >= NN) r = NN - 1;
                int g = getb(batch, r, is64);
                const float* zr = Z + (size_t)g * F + wn * 64 + l16;
#pragma unroll
                for (int nt = 0; nt < 4; nt++) {
                    float u = acc[mt][nt][reg] + zr[nt * 16];
                    float h = fmaxf(u * sc1[nt] + sh1[nt], 0.f);
                    h2[lr * 136 + wn * 64 + nt * 16 + l16] = (unsigned short)bfs(h);
                }
            }
        __syncthreads();

        floatx4 acc2[2][4];
#pragma unroll
        for (int mt = 0; mt < 2; mt++)
#pragma unroll
            for (int nt = 0; nt < 4; nt++) acc2[mt][nt] = (floatx4){0.f, 0.f, 0.f, 0.f};
#pragma unroll
        for (int kt = 0; kt < 4; kt++) {
            short8 A2[2];
#pragma unroll
            for (int mt = 0; mt < 2; mt++)
                A2[mt] = *reinterpret_cast<const short8*>(&h2[(wm * 32 + mt * 16 + l16) * 136 + kt * 32 + quad * 8]);
#pragma unroll
            for (int mt = 0; mt < 2; mt++)
#pragma unroll
                for (int nt = 0; nt < 4; nt++)
                    acc2[mt][nt] = __builtin_amdgcn_mfma_f32_16x16x32_bf16(A2[mt], Bf2[nt][kt], acc2[mt][nt], 0, 0, 0);
        }

#pragma unroll
        for (int mt = 0; mt < 2; mt++)
#pragma unroll
            for (int reg = 0; reg < 4; reg++) {
                int r = rb + mt * 16 + quad * 4 + reg;
                if (r < NN) {
#pragma unroll
                    for (int nt = 0; nt < 4; nt++)
                        out[(size_t)r * F + wn * 64 + nt * 16 + l16] = acc2[mt][nt][reg] + bb2[nt];
                }
            }
    }
}

extern "C" void kernel_launch(void* const* d_in, const int* in_sizes, int n_in,
                              void* d_out, int out_size, void* d_ws, size_t ws_size,
                              hipStream_t stream) {
    const float* x    = (const float*)d_in[0];
    // d_in[1] edge_index, d_in[2] edge_attr: unused by the reference computation
    const int*   batch= (const int*)d_in[3];
    const float* Wl   = (const float*)d_in[4];
    const float* bng  = (const float*)d_in[5];
    const float* bnb  = (const float*)d_in[6];
    const float* W1   = (const float*)d_in[7];
    const float* b1   = (const float*)d_in[8];
    const float* bn1g = (const float*)d_in[9];
    const float* bn1b = (const float*)d_in[10];
    const float* W2   = (const float*)d_in[11];
    const float* b2   = (const float*)d_in[12];
    float* out = (float*)d_out;
    char* ws = (char*)d_ws;

    // ---- new-path workspace layout ----
    const size_t OFF_XB     = 0;                       // 500000*128*2 = 128,000,000
    const size_t OFF_W1F    = 128000000;               // 32768
    const size_t OFF_W2F    = 128032768;               // 32768
    const size_t OFF_S      = 128065536;               // 5,120,000
    const size_t OFF_T      = 133185536;               // 5,120,000
    const size_t OFF_GS     = 138305536;               // 40,000
    const size_t OFF_GE     = 138345536;               // 40,000
    const size_t OFF_SUM0   = 138385536;               // 512
    const size_t OFF_SUMSQ0 = 138386048;               // 512
    const size_t OFF_SCALE0 = 138386560;               // 512
    const size_t OFF_SHIFT0 = 138387072;               // 512
    const size_t OFF_PART   = 138387584;               // 65,536
    const size_t OFF_SCALE1 = 138453120;               // 512
    const size_t OFF_SHIFT1 = 138453632;               // 512
    const size_t OFF_FLAG   = 138454144;               // 4
    const size_t NEED       = 138454148;

    if (ws_size >= NEED) {
        unsigned short* xb  = (unsigned short*)(ws + OFF_XB);
        unsigned short* W1f = (unsigned short*)(ws + OFF_W1F);
        unsigned short* W2f = (unsigned short*)(ws + OFF_W2F);
        float* S        = (float*)(ws + OFF_S);        // later reused for S2f
        float* T        = (float*)(ws + OFF_T);        // later reused for Z
        int*   gs       = (int*)  (ws + OFF_GS);
        int*   ge       = (int*)  (ws + OFF_GE);
        float* sum0     = (float*)(ws + OFF_SUM0);
        float* sumsq0   = (float*)(ws + OFF_SUMSQ0);
        float* scale0   = (float*)(ws + OFF_SCALE0);
        float* shift0   = (float*)(ws + OFF_SHIFT0);
        float* partials = (float*)(ws + OFF_PART);
        float* scale1   = (float*)(ws + OFF_SCALE1);
        float* shift1   = (float*)(ws + OFF_SHIFT1);
        int*   flag     = (int*)  (ws + OFF_FLAG);

        hipMemsetAsync(ws + OFF_GS, 0, NEED - OFF_GS, stream);

        k_detect <<<1, 256, 0, stream>>>(batch, flag);
        k_wfrag  <<<128, 256, 0, stream>>>(W1, W2, W1f, W2f);
        k_bounds <<<(NN + 255) / 256, 256, 0, stream>>>(batch, gs, ge, flag);
        k_segsum <<<NG, 256, 0, stream>>>(x, gs, ge, S, xb);
        k_rowmm  <<<NG / 2, 256, 0, stream>>>(S, Wl, nullptr, T, 0);          // T = S @ W_lin
        k_colstats<<<64, 128, 0, stream>>>(T, sum0, sumsq0);
        k_bn0    <<<1, 128, 0, stream>>>(sum0, sumsq0, bng, bnb, scale0, shift0);
        k_bnrelu <<<NG * F / 1024, 256, 0, stream>>>(T, scale0, shift0, S);   // S2f (into S space)
        k_rowmm  <<<NG / 2, 256, 0, stream>>>(S, W1, b1, T, 1);               // Z = S2f@W1 + b1 (into T)
        k_pass1  <<<2048, 256, 0, stream>>>(xb, batch, W1f, T, partials, flag);
        k_bn1    <<<1, 128, 0, stream>>>(partials, bn1g, bn1b, scale1, shift1);
        k_pass2  <<<2048, 256, 0, stream>>>(xb, batch, W1f, W2f, T, scale1, shift1, b2, out, flag);
    } else {
        // legacy layout + kernels (exact previous behavior)
        float* S        = (float*)(ws + 0);
        float* T        = (float*)(ws + 5120000);
        int*   gs       = (int*)  (ws + 10240000);
        int*   ge       = (int*)  (ws + 10280000);
        float* sum0     = (float*)(ws + 10320000);
        float* sumsq0   = (float*)(ws + 10320512);
        float* scale0   = (float*)(ws + 10321024);
        float* shift0   = (float*)(ws + 10321536);
        float* partials = (float*)(ws + 10322048);
        float* scale1   = (float*)(ws + 10387584);
        float* shift1   = (float*)(ws + 10388096);
        int*   flag     = (int*)  (ws + 10388608);

        hipMemsetAsync(ws + 10240000, 0, 147584, stream);

        k_detect <<<1, 256, 0, stream>>>(batch, flag);
        k_bounds <<<(NN + 255) / 256, 256, 0, stream>>>(batch, gs, ge, flag);
        k_segsum <<<NG, 256, 0, stream>>>(x, gs, ge, S, nullptr);
        k_rowmm  <<<NG / 2, 256, 0, stream>>>(S, Wl, nullptr, T, 0);
        k_colstats<<<64, 128, 0, stream>>>(T, sum0, sumsq0);
        k_bn0    <<<1, 128, 0, stream>>>(sum0, sumsq0, bng, bnb, scale0, shift0);
        k_bnrelu <<<NG * F / 1024, 256, 0, stream>>>(T, scale0, shift0, S);
        k_rowmm  <<<NG / 2, 256, 0, stream>>>(S, W1, b1, T, 1);
        k_pass1_old <<<2048, 256, 0, stream>>>(x, batch, W1, T, partials, flag);
        k_bn1    <<<1, 128, 0, stream>>>(partials, bn1g, bn1b, scale1, shift1);
        k_pass2_old <<<2048, 256, 64 * 136 * 2, stream>>>(x, batch, W1, W2, T, scale1, shift1, b2, out, flag);
    }
}

// Round 2
// 837.784 us; speedup vs baseline: 1.0613x; 1.0613x over previous
//
#include <hip/hip_runtime.h>
#include <hip/hip_bf16.h>
#include <cstdint>
#include <cstddef>

#define NN 500000
#define NG 10000
#define F  128
#define EPSV 1e-5f

typedef __attribute__((ext_vector_type(8))) short short8;
typedef __attribute__((ext_vector_type(4))) float floatx4;

__device__ __forceinline__ short bfs(float f) {
    __hip_bfloat16 h = __float2bfloat16(f);   // HW cvt, RNE
    union { __hip_bfloat16 h; unsigned short u; } c; c.h = h;
    return (short)c.u;
}
// batch may arrive as int32 (harness-converted) or raw int64 (little-endian, values < 10000).
__device__ __forceinline__ int getb(const int* __restrict__ b, int i, int is64) {
    return is64 ? b[2 * i] : b[i];
}

// ---- K0: detect batch dtype. Sorted int32 batch has nonzero values at odd positions >= 100001;
// int64 batch has all-zero high words there. flag = 1 -> int64.
__global__ void k_detect(const int* __restrict__ batch, int* __restrict__ flag) {
    __shared__ int nz;
    if (threadIdx.x == 0) nz = 0;
    __syncthreads();
    int j = 100001 + threadIdx.x * 1500;      // odd indices, max 482501 < 500000
    if (batch[j] != 0) atomicAdd(&nz, 1);
    __syncthreads();
    if (threadIdx.x == 0) flag[0] = (nz == 0) ? 1 : 0;
}

// ---- K1: segment boundaries (batch is sorted). Empty graphs keep start=end=0 via memset.
__global__ void k_bounds(const int* __restrict__ batch, int* __restrict__ gs, int* __restrict__ ge,
                         const int* __restrict__ flag) {
    int is64 = flag[0];
    int i = blockIdx.x * 256 + threadIdx.x;
    if (i >= NN) return;
    int b = getb(batch, i, is64);
    if (i == 0      || getb(batch, i - 1, is64) != b) gs[b] = i;
    if (i == NN - 1 || getb(batch, i + 1, is64) != b) ge[b] = i + 1;
}

// ---- K2: per-graph segment sum (fp32), one block per graph. 256 thr = 32 float4-cols x 8 rows.
//          Also emits xb = bf16(x) (fragment-consumable row-major) when xb != nullptr.
__global__ void k_segsum(const float* __restrict__ x, const int* __restrict__ gs,
                         const int* __restrict__ ge, float* __restrict__ S,
                         unsigned short* __restrict__ xb) {
    __shared__ float red[8][128];
    int g = blockIdx.x;
    int s = gs[g], e = ge[g];
    int o = threadIdx.x & 31, rl = threadIdx.x >> 5;
    float acc[4] = {0.f, 0.f, 0.f, 0.f};
    for (int r = s + rl; r < e; r += 8) {
        float4 v = *reinterpret_cast<const float4*>(x + (size_t)r * F + o * 4);
        acc[0] += v.x; acc[1] += v.y; acc[2] += v.z; acc[3] += v.w;
        if (xb) {
            ushort4 bv;
            bv.x = (unsigned short)bfs(v.x); bv.y = (unsigned short)bfs(v.y);
            bv.z = (unsigned short)bfs(v.z); bv.w = (unsigned short)bfs(v.w);
            *reinterpret_cast<ushort4*>(xb + (size_t)r * F + o * 4) = bv;
        }
    }
#pragma unroll
    for (int j = 0; j < 4; j++) red[rl][o * 4 + j] = acc[j];
    __syncthreads();
    if (threadIdx.x < 128) {
        float ssum = 0.f;
#pragma unroll
        for (int rr = 0; rr < 8; rr++) ssum += red[rr][threadIdx.x];
        S[(size_t)g * F + threadIdx.x] = ssum;
    }
}

// ---- K2b: fragment-ordered bf16 weight tables: Wf[n*128 + k] = bf16(W[k*128 + n]).
//           A lane's B-fragment chunk (8 consecutive k at fixed n) is then one 16B load.
__global__ void k_wfrag(const float* __restrict__ W1, const float* __restrict__ W2,
                        unsigned short* __restrict__ W1f, unsigned short* __restrict__ W2f) {
    int i = blockIdx.x * 256 + threadIdx.x;   // grid 128*256 = 32768 = 2*16384
    int sel = i >> 14, j = i & 16383;
    int n = j >> 7, kk = j & 127;
    const float* W = sel ? W2 : W1;
    unsigned short* Wf = sel ? W2f : W1f;
    Wf[j] = (unsigned short)bfs(W[kk * F + n]);
}

// ---- K3a/K3e: out[r][c] = (bias?) + sum_k A[r][k] * W[k][c].  10000x128, K=128, all fp32. 2 rows/block.
__global__ void k_rowmm(const float* __restrict__ A, const float* __restrict__ W,
                        const float* __restrict__ bias, float* __restrict__ out, int hasBias) {
    int r = blockIdx.x * 2 + (threadIdx.x >> 7);
    int c = threadIdx.x & 127;
    const float* a = A + (size_t)r * F;
    float acc = hasBias ? bias[c] : 0.f;
#pragma unroll 4
    for (int k = 0; k < F; k++) acc += a[k] * W[k * F + c];
    out[(size_t)r * F + c] = acc;
}

// ---- K3b: column sums / sumsq of T over 10000 rows (for BN0). grid 64 x 128.
__global__ void k_colstats(const float* __restrict__ T, float* __restrict__ sum, float* __restrict__ sumsq) {
    int f = threadIdx.x;
    int lo = blockIdx.x * 157;              // 64*157 = 10048 >= 10000
    int hi = lo + 157; if (hi > NG) hi = NG;
    float s = 0.f, q = 0.f;
    for (int r = lo; r < hi; r++) { float v = T[(size_t)r * F + f]; s += v; q += v * v; }
    atomicAdd(&sum[f], s); atomicAdd(&sumsq[f], q);
}

// ---- K3c: finalize BN0 -> per-feature scale/shift.
__global__ void k_bn0(const float* __restrict__ sum, const float* __restrict__ sumsq,
                      const float* __restrict__ g, const float* __restrict__ b,
                      float* __restrict__ scale, float* __restrict__ shift) {
    int f = threadIdx.x;
    float mu  = sum[f] / (float)NG;
    float var = sumsq[f] / (float)NG - mu * mu;
    float rs  = rsqrtf(var + EPSV);
    float sc  = g[f] * rs;
    scale[f] = sc; shift[f] = b[f] - mu * sc;
}

// ---- K3d: S2f = relu(T*scale + shift), f32. grid 1250 x 256, 4 elems/thread.
__global__ void k_bnrelu(const float* __restrict__ T, const float* __restrict__ scale,
                         const float* __restrict__ shift, float* __restrict__ S2) {
    int e = (blockIdx.x * 256 + threadIdx.x) * 4;
    float4 t = *reinterpret_cast<const float4*>(T + e);
    int c = e & 127;
    float4 o;
    o.x = fmaxf(t.x * scale[c]     + shift[c],     0.f);
    o.y = fmaxf(t.y * scale[c + 1] + shift[c + 1], 0.f);
    o.z = fmaxf(t.z * scale[c + 2] + shift[c + 2], 0.f);
    o.w = fmaxf(t.w * scale[c + 3] + shift[c + 3], 0.f);
    *reinterpret_cast<float4*>(S2 + e) = o;
}

// load 8 consecutive fp32 and convert to a bf16 A/B fragment chunk (legacy path)
__device__ __forceinline__ short8 ld8bf(const float* __restrict__ p) {
    float4 f0 = *reinterpret_cast<const float4*>(p);
    float4 f1 = *reinterpret_cast<const float4*>(p + 4);
    short8 r;
    r[0] = bfs(f0.x); r[1] = bfs(f0.y); r[2] = bfs(f0.z); r[3] = bfs(f0.w);
    r[4] = bfs(f1.x); r[5] = bfs(f1.y); r[6] = bfs(f1.z); r[7] = bfs(f1.w);
    return r;
}

// ======================= NEW PATH: bf16 x + fragment weight tables =======================

// ---- K4: pass1. u = xb@W1 + Z[batch] (Z folds b1); accumulate per-feature sum/sumsq of u.
//          Bf1 register-resident (64 VGPR), loaded once as contiguous 16B chunks from W1f.
__global__ __launch_bounds__(256, 3)
void k_pass1(const unsigned short* __restrict__ xb, const int* __restrict__ batch,
             const unsigned short* __restrict__ W1f, const float* __restrict__ Z,
             float* __restrict__ partials, const int* __restrict__ flag) {
    const int is64 = flag[0];
    const int lane = threadIdx.x & 63;
    const int wave = threadIdx.x >> 6;
    const int wm = wave & 1, wn = wave >> 1;
    const int quad = lane >> 4, l16 = lane & 15;

    short8 Bf[4][4];
#pragma unroll
    for (int nt = 0; nt < 4; nt++)
#pragma unroll
        for (int kt = 0; kt < 4; kt++)
            Bf[nt][kt] = *reinterpret_cast<const short8*>(
                W1f + (wn * 64 + nt * 16 + l16) * F + kt * 32 + quad * 8);

    float su[4], sq[4];
#pragma unroll
    for (int nt = 0; nt < 4; nt++) { su[nt] = 0.f; sq[nt] = 0.f; }

    const int NT = (NN + 63) / 64;
    for (int tile = blockIdx.x; tile < NT; tile += gridDim.x) {
        int rb = tile * 64 + wm * 32;
        floatx4 acc[2][4];
#pragma unroll
        for (int mt = 0; mt < 2; mt++)
#pragma unroll
            for (int nt = 0; nt < 4; nt++) acc[mt][nt] = (floatx4){0.f, 0.f, 0.f, 0.f};

#pragma unroll
        for (int kt = 0; kt < 4; kt++) {
            short8 A[2];
#pragma unroll
            for (int mt = 0; mt < 2; mt++) {
                int r = rb + mt * 16 + l16; if (r >= NN) r = NN - 1;
                A[mt] = *reinterpret_cast<const short8*>(xb + (size_t)r * F + kt * 32 + quad * 8);
            }
#pragma unroll
            for (int mt = 0; mt < 2; mt++)
#pragma unroll
                for (int nt = 0; nt < 4; nt++)
                    acc[mt][nt] = __builtin_amdgcn_mfma_f32_16x16x32_bf16(A[mt], Bf[nt][kt], acc[mt][nt], 0, 0, 0);
        }

#pragma unroll
        for (int mt = 0; mt < 2; mt++)
#pragma unroll
            for (int reg = 0; reg < 4; reg++) {
                int r = rb + mt * 16 + quad * 4 + reg;
                bool valid = r < NN;
                int g = getb(batch, valid ? r : NN - 1, is64);
                const float* zr = Z + (size_t)g * F + wn * 64 + l16;
#pragma unroll
                for (int nt = 0; nt < 4; nt++) {
                    float u = acc[mt][nt][reg] + zr[nt * 16];
                    if (valid) { su[nt] += u; sq[nt] += u * u; }
                }
            }
    }

    float* ps = partials + (size_t)(blockIdx.x & 63) * 256;
#pragma unroll
    for (int nt = 0; nt < 4; nt++) {
        float s = su[nt], q = sq[nt];
        s += __shfl_xor(s, 16, 64); s += __shfl_xor(s, 32, 64);
        q += __shfl_xor(q, 16, 64); q += __shfl_xor(q, 32, 64);
        if (quad == 0) {
            int col = wn * 64 + nt * 16 + l16;
            atomicAdd(&ps[col], s);
            atomicAdd(&ps[128 + col], q);
        }
    }
}

// ---- K5: finalize BN1 from 64 partial slots.
__global__ void k_bn1(const float* __restrict__ partials, const float* __restrict__ g1,
                      const float* __restrict__ b1g, float* __restrict__ scale1,
                      float* __restrict__ shift1) {
    int f = threadIdx.x;
    float s = 0.f, q = 0.f;
    for (int t = 0; t < 64; t++) { s += partials[t * 256 + f]; q += partials[t * 256 + 128 + f]; }
    float mu  = s / (float)NN;
    float var = q / (float)NN - mu * mu;
    float rs  = rsqrtf(var + EPSV);
    float sc  = g1[f] * rs;
    scale1[f] = sc; shift1[f] = b1g[f] - mu * sc;
}

// ---- K6: pass2. Bf1 in registers (64 VGPR); W2 staged once in LDS with XOR swizzle
//          (T2: kills the 16-way same-bank column read); h2 single-buffered (2 syncs/tile).
//          LDS = 32KB (w2s) + 17KB (h2) = 50KB -> 3 blocks/CU (12 waves, ~37%).
__global__ __launch_bounds__(256, 3)
void k_pass2(const unsigned short* __restrict__ xb, const int* __restrict__ batch,
             const unsigned short* __restrict__ W1f, const unsigned short* __restrict__ W2f,
             const float* __restrict__ Z, const float* __restrict__ scale1,
             const float* __restrict__ shift1, const float* __restrict__ b2,
             float* __restrict__ out, const int* __restrict__ flag) {
    __shared__ unsigned short w2s[16384];     // fragment-order W2, XOR-swizzled
    __shared__ unsigned short h2[64][136];    // +8 shorts pad
    const int is64 = flag[0];
    const int lane = threadIdx.x & 63;
    const int wave = threadIdx.x >> 6;
    const int wm = wave & 1, wn = wave >> 1;
    const int quad = lane >> 4, l16 = lane & 15;

    // stage W2f -> LDS, swizzled: j ^ ((n&7)<<3) shorts (= <<4 bytes), n = j>>7.
    // Keeps 16B alignment (bits 3-5 only), bijective within each n-row.
#pragma unroll
    for (int c = 0; c < 8; c++) {
        int j = threadIdx.x * 64 + c * 8;
        int js = j ^ (((j >> 7) & 7) << 3);
        *reinterpret_cast<short8*>(&w2s[js]) = *reinterpret_cast<const short8*>(W2f + j);
    }

    short8 Bf1[4][4];
#pragma unroll
    for (int nt = 0; nt < 4; nt++)
#pragma unroll
        for (int kt = 0; kt < 4; kt++)
            Bf1[nt][kt] = *reinterpret_cast<const short8*>(
                W1f + (wn * 64 + nt * 16 + l16) * F + kt * 32 + quad * 8);

    float sc1[4], sh1[4], bb2[4];
#pragma unroll
    for (int nt = 0; nt < 4; nt++) {
        int n = wn * 64 + nt * 16 + l16;
        sc1[nt] = scale1[n]; sh1[nt] = shift1[n]; bb2[nt] = b2[n];
    }
    const int jb2 = (wn * 64 + l16) * F + quad * 8;   // w2s base (pre-xor)
    const int X   = (l16 & 7) << 3;                   // swizzle term
    __syncthreads();                                  // w2s visible to all

    const int NT = (NN + 63) / 64;
    for (int tile = blockIdx.x; tile < NT; tile += gridDim.x) {
        int rb = tile * 64 + wm * 32;
        floatx4 acc[2][4];
#pragma unroll
        for (int mt = 0; mt < 2; mt++)
#pragma unroll
            for (int nt = 0; nt < 4; nt++) acc[mt][nt] = (floatx4){0.f, 0.f, 0.f, 0.f};

#pragma unroll
        for (int kt = 0; kt < 4; kt++) {
            short8 A[2];
#pragma unroll
            for (int mt = 0; mt < 2; mt++) {
                int r = rb + mt * 16 + l16; if (r >= NN) r = NN - 1;
                A[mt] = *reinterpret_cast<const short8*>(xb + (size_t)r * F + kt * 32 + quad * 8);
            }
#pragma unroll
            for (int mt = 0; mt < 2; mt++)
#pragma unroll
                for (int nt = 0; nt < 4; nt++)
                    acc[mt][nt] = __builtin_amdgcn_mfma_f32_16x16x32_bf16(A[mt], Bf1[nt][kt], acc[mt][nt], 0, 0, 0);
        }

        __syncthreads();   // previous tile's h2 reads complete
#pragma unroll
        for (int mt = 0; mt < 2; mt++)
#pragma unroll
            for (int reg = 0; reg < 4; reg++) {
                int lr = wm * 32 + mt * 16 + quad * 4 + reg;
                int r = tile * 64 + lr; if (r >= NN) r = NN - 1;
                int g = getb(batch, r, is64);
                const float* zr = Z + (size_t)g * F + wn * 64 + l16;
#pragma unroll
                for (int nt = 0; nt < 4; nt++) {
                    float u = acc[mt][nt][reg] + zr[nt * 16];
                    float h = fmaxf(u * sc1[nt] + sh1[nt], 0.f);
                    h2[lr][wn * 64 + nt * 16 + l16] = (unsigned short)bfs(h);
                }
            }
        __syncthreads();   // h2 ready

        floatx4 acc2[2][4];
#pragma unroll
        for (int mt = 0; mt < 2; mt++)
#pragma unroll
            for (int nt = 0; nt < 4; nt++) acc2[mt][nt] = (floatx4){0.f, 0.f, 0.f, 0.f};
#pragma unroll
        for (int kt = 0; kt < 4; kt++) {
            short8 A2[2];
#pragma unroll
            for (int mt = 0; mt < 2; mt++)
                A2[mt] = *reinterpret_cast<const short8*>(&h2[wm * 32 + mt * 16 + l16][kt * 32 + quad * 8]);
#pragma unroll
            for (int nt = 0; nt < 4; nt++) {
                int jr = (jb2 + nt * 16 * F + kt * 32) ^ X;
                short8 B = *reinterpret_cast<const short8*>(&w2s[jr]);
#pragma unroll
                for (int mt = 0; mt < 2; mt++)
                    acc2[mt][nt] = __builtin_amdgcn_mfma_f32_16x16x32_bf16(A2[mt], B, acc2[mt][nt], 0, 0, 0);
            }
        }

#pragma unroll
        for (int mt = 0; mt < 2; mt++)
#pragma unroll
            for (int reg = 0; reg < 4; reg++) {
                int r = rb + mt * 16 + quad * 4 + reg;
                if (r < NN) {
#pragma unroll
                    for (int nt = 0; nt < 4; nt++)
                        out[(size_t)r * F + wn * 64 + nt * 16 + l16] = acc2[mt][nt][reg] + bb2[nt];
                }
            }
    }
}

// ======================= LEGACY PATH (used only if workspace too small) =======================

__global__ __launch_bounds__(256, 2)
void k_pass1_old(const float* __restrict__ x, const int* __restrict__ batch,
                 const float* __restrict__ W1, const float* __restrict__ Z,
                 float* __restrict__ partials, const int* __restrict__ flag) {
    const int is64 = flag[0];
    const int lane = threadIdx.x & 63;
    const int wave = threadIdx.x >> 6;
    const int wm = wave & 1, wn = wave >> 1;
    const int quad = lane >> 4, l16 = lane & 15;

    short8 Bf[4][4];
#pragma unroll
    for (int nt = 0; nt < 4; nt++) {
        int n = wn * 64 + nt * 16 + l16;
#pragma unroll
        for (int kt = 0; kt < 4; kt++)
#pragma unroll
            for (int j = 0; j < 8; j++)
                Bf[nt][kt][j] = bfs(W1[(kt * 32 + quad * 8 + j) * F + n]);
    }

    float su[4], sq[4];
#pragma unroll
    for (int nt = 0; nt < 4; nt++) { su[nt] = 0.f; sq[nt] = 0.f; }

    const int NT = (NN + 63) / 64;
    for (int tile = blockIdx.x; tile < NT; tile += gridDim.x) {
        int rb = tile * 64 + wm * 32;
        floatx4 acc[2][4];
#pragma unroll
        for (int mt = 0; mt < 2; mt++)
#pragma unroll
            for (int nt = 0; nt < 4; nt++) acc[mt][nt] = (floatx4){0.f, 0.f, 0.f, 0.f};

#pragma unroll
        for (int kt = 0; kt < 4; kt++) {
            short8 A[2];
#pragma unroll
            for (int mt = 0; mt < 2; mt++) {
                int r = rb + mt * 16 + l16; if (r >= NN) r = NN - 1;
                A[mt] = ld8bf(x + (size_t)r * F + kt * 32 + quad * 8);
            }
#pragma unroll
            for (int mt = 0; mt < 2; mt++)
#pragma unroll
                for (int nt = 0; nt < 4; nt++)
                    acc[mt][nt] = __builtin_amdgcn_mfma_f32_16x16x32_bf16(A[mt], Bf[nt][kt], acc[mt][nt], 0, 0, 0);
        }

#pragma unroll
        for (int mt = 0; mt < 2; mt++)
#pragma unroll
            for (int reg = 0; reg < 4; reg++) {
                int r = rb + mt * 16 + quad * 4 + reg;
                bool valid = r < NN;
                int g = getb(batch, valid ? r : NN - 1, is64);
                const float* zr = Z + (size_t)g * F + wn * 64 + l16;
#pragma unroll
                for (int nt = 0; nt < 4; nt++) {
                    float u = acc[mt][nt][reg] + zr[nt * 16];
                    if (valid) { su[nt] += u; sq[nt] += u * u; }
                }
            }
    }

    float* ps = partials + (size_t)(blockIdx.x & 63) * 256;
#pragma unroll
    for (int nt = 0; nt < 4; nt++) {
        float s = su[nt], q = sq[nt];
        s += __shfl_xor(s, 16, 64); s += __shfl_xor(s, 32, 64);
        q += __shfl_xor(q, 16, 64); q += __shfl_xor(q, 32, 64);
        if (quad == 0) {
            int col = wn * 64 + nt * 16 + l16;
            atomicAdd(&ps[col], s);
            atomicAdd(&ps[128 + col], q);
        }
    }
}

__global__ __launch_bounds__(256, 2)
void k_pass2_old(const float* __restrict__ x, const int* __restrict__ batch,
                 const float* __restrict__ W1, const float* __restrict__ W2,
                 const float* __restrict__ Z, const float* __restrict__ scale1,
                 const float* __restrict__ shift1, const float* __restrict__ b2,
                 float* __restrict__ out, const int* __restrict__ flag) {
    extern __shared__ unsigned short h2e[];   // [64][136]
    const int is64 = flag[0];
    const int lane = threadIdx.x & 63;
    const int wave = threadIdx.x >> 6;
    const int wm = wave & 1, wn = wave >> 1;
    const int quad = lane >> 4, l16 = lane & 15;

    short8 Bf1[4][4], Bf2[4][4];
    float sc1[4], sh1[4], bb2[4];
#pragma unroll
    for (int nt = 0; nt < 4; nt++) {
        int n = wn * 64 + nt * 16 + l16;
        sc1[nt] = scale1[n]; sh1[nt] = shift1[n]; bb2[nt] = b2[n];
#pragma unroll
        for (int kt = 0; kt < 4; kt++)
#pragma unroll
            for (int j = 0; j < 8; j++) {
                int k = kt * 32 + quad * 8 + j;
                Bf1[nt][kt][j] = bfs(W1[k * F + n]);
                Bf2[nt][kt][j] = bfs(W2[k * F + n]);
            }
    }

    const int NT = (NN + 63) / 64;
    for (int tile = blockIdx.x; tile < NT; tile += gridDim.x) {
        int rb = tile * 64 + wm * 32;
        floatx4 acc[2][4];
#pragma unroll
        for (int mt = 0; mt < 2; mt++)
#pragma unroll
            for (int nt = 0; nt < 4; nt++) acc[mt][nt] = (floatx4){0.f, 0.f, 0.f, 0.f};

#pragma unroll
        for (int kt = 0; kt < 4; kt++) {
            short8 A[2];
#pragma unroll
            for (int mt = 0; mt < 2; mt++) {
                int r = rb + mt * 16 + l16; if (r >= NN) r = NN - 1;
                A[mt] = ld8bf(x + (size_t)r * F + kt * 32 + quad * 8);
            }
#pragma unroll
            for (int mt = 0; mt < 2; mt++)
#pragma unroll
                for (int nt = 0; nt < 4; nt++)
                    acc[mt][nt] = __builtin_amdgcn_mfma_f32_16x16x32_bf16(A[mt], Bf1[nt][kt], acc[mt][nt], 0, 0, 0);
        }

        __syncthreads();
#pragma unroll
        for (int mt = 0; mt < 2; mt++)
#pragma unroll
            for (int reg = 0; reg < 4; reg++) {
                int lr = wm * 32 + mt * 16 + quad * 4 + reg;
                int r = tile * 64 + lr; if (r >= NN) r = NN - 1;
                int g = getb(batch, r, is64);
                const float* zr = Z + (size_t)g * F + wn * 64 + l16;
#pragma unroll
                for (int nt = 0; nt < 4; nt++) {
                    float u = acc[mt][nt][reg] + zr[nt * 16];
                    float h = fmaxf(u * sc1[nt] + sh1[nt], 0.f);
                    h2e[lr * 136 + wn * 64 + nt * 16 + l16] = (unsigned short)bfs(h);
                }
            }
        __syncthreads();

        floatx4 acc2[2][4];
#pragma unroll
        for (int mt = 0; mt < 2; mt++)
#pragma unroll
            for (int nt = 0; nt < 4; nt++) acc2[mt][nt] = (floatx4){0.f, 0.f, 0.f, 0.f};
#pragma unroll
        for (int kt = 0; kt < 4; kt++) {
            short8 A2[2];
#pragma unroll
            for (int mt = 0; mt < 2; mt++)
                A2[mt] = *reinterpret_cast<const short8*>(&h2e[(wm * 32 + mt * 16 + l16) * 136 + kt * 32 + quad * 8]);
#pragma unroll
            for (int mt = 0; mt < 2; mt++)
#pragma unroll
                for (int nt = 0; nt < 4; nt++)
                    acc2[mt][nt] = __builtin_amdgcn_mfma_f32_16x16x32_bf16(A2[mt], Bf2[nt][kt], acc2[mt][nt], 0, 0, 0);
        }

#pragma unroll
        for (int mt = 0; mt < 2; mt++)
#pragma unroll
            for (int reg = 0; reg < 4; reg++) {
                int r = rb + mt * 16 + quad * 4 + reg;
                if (r < NN) {
#pragma unroll
                    for (int nt = 0; nt < 4; nt++)
                        out[(size_t)r * F + wn * 64 + nt * 16 + l16] = acc2[mt][nt][reg] + bb2[nt];
                }
            }
    }
}

extern "C" void kernel_launch(void* const* d_in, const int* in_sizes, int n_in,
                              void* d_out, int out_size, void* d_ws, size_t ws_size,
                              hipStream_t stream) {
    const float* x    = (const float*)d_in[0];
    // d_in[1] edge_index, d_in[2] edge_attr: unused by the reference computation
    const int*   batch= (const int*)d_in[3];
    const float* Wl   = (const float*)d_in[4];
    const float* bng  = (const float*)d_in[5];
    const float* bnb  = (const float*)d_in[6];
    const float* W1   = (const float*)d_in[7];
    const float* b1   = (const float*)d_in[8];
    const float* bn1g = (const float*)d_in[9];
    const float* bn1b = (const float*)d_in[10];
    const float* W2   = (const float*)d_in[11];
    const float* b2   = (const float*)d_in[12];
    float* out = (float*)d_out;
    char* ws = (char*)d_ws;

    // ---- new-path workspace layout ----
    const size_t OFF_XB     = 0;                       // 500000*128*2 = 128,000,000
    const size_t OFF_W1F    = 128000000;               // 32768
    const size_t OFF_W2F    = 128032768;               // 32768
    const size_t OFF_S      = 128065536;               // 5,120,000
    const size_t OFF_T      = 133185536;               // 5,120,000
    const size_t OFF_GS     = 138305536;               // 40,000
    const size_t OFF_GE     = 138345536;               // 40,000
    const size_t OFF_SUM0   = 138385536;               // 512
    const size_t OFF_SUMSQ0 = 138386048;               // 512
    const size_t OFF_SCALE0 = 138386560;               // 512
    const size_t OFF_SHIFT0 = 138387072;               // 512
    const size_t OFF_PART   = 138387584;               // 65,536
    const size_t OFF_SCALE1 = 138453120;               // 512
    const size_t OFF_SHIFT1 = 138453632;               // 512
    const size_t OFF_FLAG   = 138454144;               // 4
    const size_t NEED       = 138454148;

    if (ws_size >= NEED) {
        unsigned short* xb  = (unsigned short*)(ws + OFF_XB);
        unsigned short* W1f = (unsigned short*)(ws + OFF_W1F);
        unsigned short* W2f = (unsigned short*)(ws + OFF_W2F);
        float* S        = (float*)(ws + OFF_S);        // later reused for S2f
        float* T        = (float*)(ws + OFF_T);        // later reused for Z
        int*   gs       = (int*)  (ws + OFF_GS);
        int*   ge       = (int*)  (ws + OFF_GE);
        float* sum0     = (float*)(ws + OFF_SUM0);
        float* sumsq0   = (float*)(ws + OFF_SUMSQ0);
        float* scale0   = (float*)(ws + OFF_SCALE0);
        float* shift0   = (float*)(ws + OFF_SHIFT0);
        float* partials = (float*)(ws + OFF_PART);
        float* scale1   = (float*)(ws + OFF_SCALE1);
        float* shift1   = (float*)(ws + OFF_SHIFT1);
        int*   flag     = (int*)  (ws + OFF_FLAG);

        hipMemsetAsync(ws + OFF_GS, 0, NEED - OFF_GS, stream);

        k_detect <<<1, 256, 0, stream>>>(batch, flag);
        k_wfrag  <<<128, 256, 0, stream>>>(W1, W2, W1f, W2f);
        k_bounds <<<(NN + 255) / 256, 256, 0, stream>>>(batch, gs, ge, flag);
        k_segsum <<<NG, 256, 0, stream>>>(x, gs, ge, S, xb);
        k_rowmm  <<<NG / 2, 256, 0, stream>>>(S, Wl, nullptr, T, 0);          // T = S @ W_lin
        k_colstats<<<64, 128, 0, stream>>>(T, sum0, sumsq0);
        k_bn0    <<<1, 128, 0, stream>>>(sum0, sumsq0, bng, bnb, scale0, shift0);
        k_bnrelu <<<NG * F / 1024, 256, 0, stream>>>(T, scale0, shift0, S);   // S2f (into S space)
        k_rowmm  <<<NG / 2, 256, 0, stream>>>(S, W1, b1, T, 1);               // Z = S2f@W1 + b1 (into T)
        k_pass1  <<<2048, 256, 0, stream>>>(xb, batch, W1f, T, partials, flag);
        k_bn1    <<<1, 128, 0, stream>>>(partials, bn1g, bn1b, scale1, shift1);
        k_pass2  <<<2048, 256, 0, stream>>>(xb, batch, W1f, W2f, T, scale1, shift1, b2, out, flag);
    } else {
        // legacy layout + kernels
        float* S        = (float*)(ws + 0);
        float* T        = (float*)(ws + 5120000);
        int*   gs       = (int*)  (ws + 10240000);
        int*   ge       = (int*)  (ws + 10280000);
        float* sum0     = (float*)(ws + 10320000);
        float* sumsq0   = (float*)(ws + 10320512);
        float* scale0   = (float*)(ws + 10321024);
        float* shift0   = (float*)(ws + 10321536);
        float* partials = (float*)(ws + 10322048);
        float* scale1   = (float*)(ws + 10387584);
        float* shift1   = (float*)(ws + 10388096);
        int*   flag     = (int*)  (ws + 10388608);

        hipMemsetAsync(ws + 10240000, 0, 147584, stream);

        k_detect <<<1, 256, 0, stream>>>(batch, flag);
        k_bounds <<<(NN + 255) / 256, 256, 0, stream>>>(batch, gs, ge, flag);
        k_segsum <<<NG, 256, 0, stream>>>(x, gs, ge, S, nullptr);
        k_rowmm  <<<NG / 2, 256, 0, stream>>>(S, Wl, nullptr, T, 0);
        k_colstats<<<64, 128, 0, stream>>>(T, sum0, sumsq0);
        k_bn0    <<<1, 128, 0, stream>>>(sum0, sumsq0, bng, bnb, scale0, shift0);
        k_bnrelu <<<NG * F / 1024, 256, 0, stream>>>(T, scale0, shift0, S);
        k_rowmm  <<<NG / 2, 256, 0, stream>>>(S, W1, b1, T, 1);
        k_pass1_old <<<2048, 256, 0, stream>>>(x, batch, W1, T, partials, flag);
        k_bn1    <<<1, 128, 0, stream>>>(partials, bn1g, bn1b, scale1, shift1);
        k_pass2_old <<<2048, 256, 64 * 136 * 2, stream>>>(x, batch, W1, W2, T, scale1, shift1, b2, out, flag);
    }
}